// Round 5
// baseline (145.216 us; speedup 1.0000x reference)
//
#include <hip/hip_runtime.h>
#include <math.h>

constexpr int N_NODES = 2000;
constexpr int F_IN    = 512;
constexpr int H       = 64;
constexpr int SLOT_SH = 8;        // 256 slots/node (max degree ~105 << 256)
constexpr int GBLK    = 1664;     // gather blocks in mega kernel

// --------------------------------------------------------------- GEMM tile
// C[64x64] tile of A[M x K] @ W[K x 64], 256 threads, 4x4 micro-tile,
// BK=32 (LDS 16.6 KB so the merged kernel isn't LDS-occupancy-capped).
__device__ __forceinline__ void gemm_tile256(
    const float* __restrict__ A, const float* __restrict__ W,
    float (*As)[33], float (*Ws)[64],
    int r0, int K, float* __restrict__ C)
{
  int t  = threadIdx.x;
  int tx = t & 15, ty = t >> 4;
  float acc[4][4] = {};
  for (int k0 = 0; k0 < K; k0 += 32) {
    #pragma unroll
    for (int i = 0; i < 8; i++) {
      int idx = t + i * 256;
      int row = idx >> 5, kk = idx & 31;
      int gr = r0 + row;
      As[row][kk] = (gr < N_NODES) ? A[(size_t)gr * K + k0 + kk] : 0.f;
    }
    #pragma unroll
    for (int i = 0; i < 8; i++) {
      int idx = t + i * 256;
      int kk = idx >> 6, col = idx & 63;
      Ws[kk][col] = W[(size_t)(k0 + kk) * H + col];
    }
    __syncthreads();
    #pragma unroll
    for (int kk = 0; kk < 32; kk++) {
      float4 wv = *reinterpret_cast<const float4*>(&Ws[kk][tx * 4]);
      float av[4];
      #pragma unroll
      for (int r = 0; r < 4; r++) av[r] = As[ty * 4 + r][kk];
      #pragma unroll
      for (int r = 0; r < 4; r++) {
        acc[r][0] = fmaf(av[r], wv.x, acc[r][0]);
        acc[r][1] = fmaf(av[r], wv.y, acc[r][1]);
        acc[r][2] = fmaf(av[r], wv.z, acc[r][2]);
        acc[r][3] = fmaf(av[r], wv.w, acc[r][3]);
      }
    }
    __syncthreads();
  }
  #pragma unroll
  for (int r = 0; r < 4; r++) {
    int gr = r0 + ty * 4 + r;
    if (gr < N_NODES) {
      *reinterpret_cast<float4*>(&C[(size_t)gr * H + tx * 4]) =
          make_float4(acc[r][0], acc[r][1], acc[r][2], acc[r][3]);
    }
  }
}

// ------------------------------------------------------------- mega kernel
// blocks [0, GBLK):              sim-row gather + sim.lw -> sl[q]  (long pole)
// blocks [GBLK, GBLK+eblocks):   edge pass (deg atomics + slot-CSR, unscaled)
// blocks [GBLK+eblocks, +128):   the 4 layer-1 GEMMs (plain store)
// All three sections are mutually independent -> full overlap in one dispatch.
__global__ __launch_bounds__(256) void mega_kernel(
    const float* __restrict__ real, const float* __restrict__ imag,
    const float* __restrict__ W1,
    const int* __restrict__ ei, const float* __restrict__ ew,
    const int* __restrict__ qe, const float* __restrict__ emb,
    const float* __restrict__ lw,
    float* __restrict__ deg, int* __restrict__ cnt,
    int* __restrict__ nbr, float* __restrict__ cra, float* __restrict__ cia,
    float* __restrict__ P0r, float* __restrict__ P0i,
    float* __restrict__ P1r, float* __restrict__ P1i,
    float2* __restrict__ sl, int E, int Qn, int eblocks)
{
  __shared__ float As[64][33];
  __shared__ float Ws[32][64];
  int b = blockIdx.x;
  if (b < GBLK) {
    // ---- sim gather: 16 lanes/query, float4/lane, 2-query ILP
    const float2* lw2 = reinterpret_cast<const float2*>(lw);
    int l = threadIdx.x & 15;
    float2 wa = lw2[256 + 4 * l];
    float2 wb = lw2[257 + 4 * l];
    float2 wc = lw2[258 + 4 * l];
    float2 wd = lw2[259 + 4 * l];
    int g0 = (b * 256 + threadIdx.x) >> 4;
    int ng = (GBLK * 256) >> 4;                     // 26624 groups
    const float4* emb4 = reinterpret_cast<const float4*>(emb);
    for (int q = g0; q < Qn; q += 2 * ng) {
      int q2 = q + ng;
      bool has2 = q2 < Qn;
      int ni0 = qe[2 * q], nj0 = qe[2 * q + 1];
      int ni1 = has2 ? qe[2 * q2] : ni0;
      int nj1 = has2 ? qe[2 * q2 + 1] : nj0;
      float4 sa = emb4[((size_t)ni0 * N_NODES + nj0) * 16 + l];
      float4 sb = emb4[((size_t)ni1 * N_NODES + nj1) * 16 + l];
      float a0 = sa.x * wa.x + sa.y * wb.x + sa.z * wc.x + sa.w * wd.x;
      float a1 = sa.x * wa.y + sa.y * wb.y + sa.z * wc.y + sa.w * wd.y;
      float b0 = sb.x * wa.x + sb.y * wb.x + sb.z * wc.x + sb.w * wd.x;
      float b1 = sb.x * wa.y + sb.y * wb.y + sb.z * wc.y + sb.w * wd.y;
      #pragma unroll
      for (int off = 1; off < 16; off <<= 1) {
        a0 += __shfl_xor(a0, off, 64);
        a1 += __shfl_xor(a1, off, 64);
        b0 += __shfl_xor(b0, off, 64);
        b1 += __shfl_xor(b1, off, 64);
      }
      if (l == 0) {
        sl[q] = make_float2(a0, a1);
        if (has2) sl[q2] = make_float2(b0, b1);
      }
    }
  } else if (b < GBLK + eblocks) {
    // ---- edge pass: degree atomics + slot-CSR with UNSCALED coeffs
    int e = (b - GBLK) * 256 + threadIdx.x;
    if (e < E) {
      int s = ei[e], d = ei[E + e];
      float ww = ew[e];
      float aw = fabsf(0.5f * ww);
      atomicAdd(&deg[d], aw);
      atomicAdd(&deg[s], aw);
      float sn, cs;
      sincosf(1.5707963267948966f * ww, &sn, &cs);
      float cr = -0.5f * ww * cs;
      float ci = -0.5f * ww * sn;
      int p1 = atomicAdd(&cnt[d], 1);
      int i1 = (d << SLOT_SH) + p1;
      nbr[i1] = s; cra[i1] = cr; cia[i1] = ci;
      int p2 = atomicAdd(&cnt[s], 1);
      int i2 = (s << SLOT_SH) + p2;
      nbr[i2] = d; cra[i2] = cr; cia[i2] = -ci;
    }
  } else {
    // ---- layer-1 GEMMs
    int bi = b - GBLK - eblocks;
    int which = bi & 3, tile = bi >> 2;
    const float* A = (which & 1) ? imag : real;
    const float* W = W1 + (size_t)(which >> 1) * F_IN * H;
    float* C = (which == 0) ? P0r : (which == 1) ? P0i
             : (which == 2) ? P1r : P1i;
    gemm_tile256(A, W, As, Ws, tile * 64, F_IN, C);
  }
}

// ------------------------------- aggregation core (block/node, 4-wave split)
__device__ __forceinline__ void agg_partial(
    const int* __restrict__ cnt, const int* __restrict__ nbr,
    const float* __restrict__ cra, const float* __restrict__ cia,
    const float* __restrict__ deg,
    const float* __restrict__ Pr, const float* __restrict__ Pi,
    int v, int h, int wv, float& aro, float& aio)
{
  int cv = cnt[v];
  float ar = 0.f, ai = 0.f;
  for (int j = wv; j < cv; j += 4) {
    int idx = (v << SLOT_SH) + j;
    int u = nbr[idx];
    float dg = deg[u];
    float du = (dg > 0.f) ? rsqrtf(dg) : 0.f;
    float cr = cra[idx] * du, ci = cia[idx] * du;
    float pr = Pr[u * H + h];
    float pi = Pi[u * H + h];
    ar = fmaf(cr, pr, ar); ar = fmaf(-ci, pi, ar);
    ai = fmaf(cr, pi, ai); ai = fmaf( ci, pr, ai);
  }
  aro = ar; aio = ai;
}

__global__ __launch_bounds__(256) void aggregate1_kernel(
    const int* __restrict__ cnt, const int* __restrict__ nbr,
    const float* __restrict__ cra, const float* __restrict__ cia,
    const float* __restrict__ deg,
    const float* __restrict__ P0r, const float* __restrict__ P0i,
    const float* __restrict__ P1r, const float* __restrict__ P1i,
    float* __restrict__ xr, float* __restrict__ xi)
{
  __shared__ float sr[4][64], si[4][64];
  int v = blockIdx.x;
  int h = threadIdx.x & 63;
  int wv = threadIdx.x >> 6;
  float ar, ai;
  agg_partial(cnt, nbr, cra, cia, deg, P1r, P1i, v, h, wv, ar, ai);
  sr[wv][h] = ar; si[wv][h] = ai;
  __syncthreads();
  if (wv == 0) {
    float dgv = deg[v];
    float dv = (dgv > 0.f) ? rsqrtf(dgv) : 0.f;
    ar = (sr[0][h] + sr[1][h] + sr[2][h] + sr[3][h]) * dv + P0r[v * H + h];
    ai = (si[0][h] + si[1][h] + si[2][h] + si[3][h]) * dv + P0i[v * H + h];
    if (ar < 0.f) { ar = 0.f; ai = 0.f; }
    xr[v * H + h] = ar;
    xi[v * H + h] = ai;
  }
}

// -------------------------------------------------------------- layer-2 GEMM
__global__ __launch_bounds__(256) void gemm2_kernel(
    const float* __restrict__ xr, const float* __restrict__ xi,
    const float* __restrict__ W2,
    float* __restrict__ P0r, float* __restrict__ P0i,
    float* __restrict__ P1r, float* __restrict__ P1i)
{
  __shared__ float As[64][33];
  __shared__ float Ws[32][64];
  int bi = blockIdx.x;
  int which = bi & 3, tile = bi >> 2;
  const float* A = (which & 1) ? xi : xr;
  const float* W = W2 + (size_t)(which >> 1) * H * H;
  float* C = (which == 0) ? P0r : (which == 1) ? P0i
           : (which == 2) ? P1r : P1i;
  gemm_tile256(A, W, As, Ws, tile * 64, H, C);
}

// -------------------- layer-2 aggregation + ReLU + per-node partial logits
__global__ __launch_bounds__(256) void aggregate2_kernel(
    const int* __restrict__ cnt, const int* __restrict__ nbr,
    const float* __restrict__ cra, const float* __restrict__ cia,
    const float* __restrict__ deg,
    const float* __restrict__ P0r, const float* __restrict__ P0i,
    const float* __restrict__ P1r, const float* __restrict__ P1i,
    const float* __restrict__ lw, const float* __restrict__ lb,
    float4* __restrict__ nuw)
{
  __shared__ float sr[4][64], si[4][64];
  int v = blockIdx.x;
  int h = threadIdx.x & 63;
  int wv = threadIdx.x >> 6;
  float ar, ai;
  agg_partial(cnt, nbr, cra, cia, deg, P1r, P1i, v, h, wv, ar, ai);
  sr[wv][h] = ar; si[wv][h] = ai;
  __syncthreads();
  if (wv == 0) {
    float dgv = deg[v];
    float dv = (dgv > 0.f) ? rsqrtf(dgv) : 0.f;
    ar = (sr[0][h] + sr[1][h] + sr[2][h] + sr[3][h]) * dv + P0r[v * H + h];
    ai = (si[0][h] + si[1][h] + si[2][h] + si[3][h]) * dv + P0i[v * H + h];
    if (ar < 0.f) { ar = 0.f; ai = 0.f; }
    const float2* lw2 = reinterpret_cast<const float2*>(lw);
    float2 l0 = lw2[h], l1 = lw2[64 + h], l2 = lw2[128 + h], l3 = lw2[192 + h];
    float u0 = ar * l0.x + ai * l2.x;
    float u1 = ar * l0.y + ai * l2.y;
    float w0 = ar * l1.x + ai * l3.x;
    float w1 = ar * l1.y + ai * l3.y;
    #pragma unroll
    for (int off = 1; off < 64; off <<= 1) {
      u0 += __shfl_xor(u0, off, 64);
      u1 += __shfl_xor(u1, off, 64);
      w0 += __shfl_xor(w0, off, 64);
      w1 += __shfl_xor(w1, off, 64);
    }
    if (h == 0)
      nuw[v] = make_float4(u0 + lb[0], u1 + lb[1], w0, w1);
  }
}

// ------------------------------------------------------------ final head
// 1 thread/query: out[q] = log_softmax(sl[q] + u[ni] + w[nj])
__global__ __launch_bounds__(256) void head_kernel(
    const int* __restrict__ qe, const float2* __restrict__ sl,
    const float4* __restrict__ nuw, float2* __restrict__ out, int Qn)
{
  int q = blockIdx.x * 256 + threadIdx.x;
  if (q >= Qn) return;
  int2 nij = reinterpret_cast<const int2*>(qe)[q];
  float2 s = sl[q];
  float4 ui = nuw[nij.x];
  float4 wj = nuw[nij.y];
  float lg0 = s.x + ui.x + wj.z;
  float lg1 = s.y + ui.y + wj.w;
  float m = fmaxf(lg0, lg1);
  float lse = m + logf(expf(lg0 - m) + expf(lg1 - m));
  out[q] = make_float2(lg0 - lse, lg1 - lse);
}

// ------------------------------------------------------------------- launcher
extern "C" void kernel_launch(void* const* d_in, const int* in_sizes, int n_in,
                              void* d_out, int out_size, void* d_ws, size_t ws_size,
                              hipStream_t stream)
{
  const float* real = (const float*)d_in[0];
  const float* imag = (const float*)d_in[1];
  const int*   ei   = (const int*)d_in[2];
  const int*   qe   = (const int*)d_in[3];
  const float* emb  = (const float*)d_in[4];
  const float* ew   = (const float*)d_in[5];
  const float* W1   = (const float*)d_in[6];
  const float* W2   = (const float*)d_in[7];
  const float* lw   = (const float*)d_in[8];
  const float* lb   = (const float*)d_in[9];
  float2* out = (float2*)d_out;

  int E = in_sizes[2] / 2;
  int Q = in_sizes[3] / 2;
  int n = N_NODES;
  int nslots = N_NODES << SLOT_SH;   // 512000

  char* ws = (char*)d_ws;
  size_t off = 0;
  auto alloc = [&](size_t bytes) -> char* {
    char* p = ws + off;
    off = (off + bytes + 255) & ~(size_t)255;
    return p;
  };
  float*  deg = (float*)alloc(2048 * 4);   // deg+cnt adjacent: one 16KB memset
  int*    cnt = (int*)  alloc(2048 * 4);
  int*    nbr = (int*)  alloc((size_t)nslots * 4);
  float*  cra = (float*)alloc((size_t)nslots * 4);
  float*  cia = (float*)alloc((size_t)nslots * 4);
  float*  P0r = (float*)alloc((size_t)n * H * 4);
  float*  P0i = (float*)alloc((size_t)n * H * 4);
  float*  P1r = (float*)alloc((size_t)n * H * 4);
  float*  P1i = (float*)alloc((size_t)n * H * 4);
  float*  xr1 = (float*)alloc((size_t)n * H * 4);
  float*  xi1 = (float*)alloc((size_t)n * H * 4);
  float4* nuw = (float4*)alloc((size_t)n * 16);
  float2* sl  = (float2*)alloc((size_t)Q * 8);

  hipMemsetAsync(deg, 0, 2 * 2048 * 4, stream);           // 16 KB only

  int eblocks = (E + 255) / 256;                          // 250
  mega_kernel<<<GBLK + eblocks + 128, 256, 0, stream>>>(
      real, imag, W1, ei, ew, qe, emb, lw,
      deg, cnt, nbr, cra, cia, P0r, P0i, P1r, P1i, sl, E, Q, eblocks);
  aggregate1_kernel<<<n, 256, 0, stream>>>(cnt, nbr, cra, cia, deg,
                                           P0r, P0i, P1r, P1i, xr1, xi1);
  gemm2_kernel<<<128, 256, 0, stream>>>(xr1, xi1, W2, P0r, P0i, P1r, P1i);
  aggregate2_kernel<<<n, 256, 0, stream>>>(cnt, nbr, cra, cia, deg,
                                           P0r, P0i, P1r, P1i, lw, lb, nuw);
  head_kernel<<<(Q + 255) / 256, 256, 0, stream>>>(qe, sl, nuw, out, Q);
}